// Round 14
// baseline (89.455 us; speedup 1.0000x reference)
//
#include <hip/hip_runtime.h>
#include <hip/hip_bf16.h>
#include <math.h>

#define T_STEPS 64
#define BATCH   256
#define NX      512
#define NH      512

// LDS-visibility-only barrier: does NOT drain vmcnt, so in-flight global
// loads/stores cross it freely. Safe in scan_kernel because all global
// traffic there is same-thread per address (see kernel comment).
#define BARRIER_LGKM() asm volatile("s_waitcnt lgkmcnt(0)\n\ts_barrier" ::: "memory")

typedef short bf16x8 __attribute__((ext_vector_type(8)));
typedef float f32x4  __attribute__((ext_vector_type(4)));

// ---------------------------------------------------------------------------
// Kernel 1: P[r][h] = b1[h] + sum_k X[r][k] * W1[h][k]   (bf16 MFMA, f32 acc)
//   (unchanged — r13 double-buffered version, verified)
// ---------------------------------------------------------------------------
__global__ __launch_bounds__(256) void gemm_bf16_kernel(
    const float* __restrict__ X,    // [16384][512]
    const float* __restrict__ W1,   // [512][512]
    const float* __restrict__ b1,   // [512]
    float* __restrict__ P)          // [16384][512]
{
    __shared__ unsigned short lds[2][16384];  // 64 KB: [buf][A 8192 | B 8192]

    const int tid  = threadIdx.x;
    const int lane = tid & 63;
    const int wave = tid >> 6;
    const int wm   = wave >> 1;
    const int wn   = wave & 1;
    const int rbase = blockIdx.x * 128;
    const int nbase = blockIdx.y * 128;

    int srow[4], skof[4];
#pragma unroll
    for (int i = 0; i < 4; ++i) {
        int g = tid + i * 256;
        int ks = g >> 9, ms = (g >> 6) & 7, l = g & 63;
        srow[i] = ms * 16 + (l & 15);
        skof[i] = ks * 32 + (l >> 4) * 8;
    }

    f32x4 acc[4][4] = {};
    float4 ra[4][2], rb[4][2];

#pragma unroll
    for (int i = 0; i < 4; ++i) {
        const float* sa = &X [(size_t)(rbase + srow[i]) * 512 + skof[i]];
        const float* sb = &W1[(size_t)(nbase + srow[i]) * 512 + skof[i]];
        ra[i][0] = *(const float4*)sa;  ra[i][1] = *(const float4*)(sa + 4);
        rb[i][0] = *(const float4*)sb;  rb[i][1] = *(const float4*)(sb + 4);
    }
#pragma unroll
    for (int i = 0; i < 4; ++i) {
        int g = tid + i * 256;
        union { __hip_bfloat162 q[4]; int4 pk; } ua, ub;
        ua.q[0] = __float22bfloat162_rn(make_float2(ra[i][0].x, ra[i][0].y));
        ua.q[1] = __float22bfloat162_rn(make_float2(ra[i][0].z, ra[i][0].w));
        ua.q[2] = __float22bfloat162_rn(make_float2(ra[i][1].x, ra[i][1].y));
        ua.q[3] = __float22bfloat162_rn(make_float2(ra[i][1].z, ra[i][1].w));
        ub.q[0] = __float22bfloat162_rn(make_float2(rb[i][0].x, rb[i][0].y));
        ub.q[1] = __float22bfloat162_rn(make_float2(rb[i][0].z, rb[i][0].w));
        ub.q[2] = __float22bfloat162_rn(make_float2(rb[i][1].x, rb[i][1].y));
        ub.q[3] = __float22bfloat162_rn(make_float2(rb[i][1].z, rb[i][1].w));
        *(int4*)&lds[0][g * 8]        = ua.pk;
        *(int4*)&lds[0][8192 + g * 8] = ub.pk;
    }
#pragma unroll
    for (int i = 0; i < 4; ++i) {
        const float* sa = &X [(size_t)(rbase + srow[i]) * 512 + 64 + skof[i]];
        const float* sb = &W1[(size_t)(nbase + srow[i]) * 512 + 64 + skof[i]];
        ra[i][0] = *(const float4*)sa;  ra[i][1] = *(const float4*)(sa + 4);
        rb[i][0] = *(const float4*)sb;  rb[i][1] = *(const float4*)(sb + 4);
    }

    int p = 0;
#pragma unroll
    for (int it = 0; it < 8; ++it) {
        asm volatile("s_waitcnt lgkmcnt(0)\n\ts_barrier" ::: "memory");

        {
            bf16x8 afr[4], bfr[4];
#pragma unroll
            for (int mf = 0; mf < 4; ++mf)
                afr[mf] = *(const bf16x8*)&lds[p][((wm * 4 + mf) * 64 + lane) * 8];
#pragma unroll
            for (int nf = 0; nf < 4; ++nf)
                bfr[nf] = *(const bf16x8*)&lds[p][8192 + ((wn * 4 + nf) * 64 + lane) * 8];
#pragma unroll
            for (int mf = 0; mf < 4; ++mf)
#pragma unroll
                for (int nf = 0; nf < 4; ++nf)
                    acc[mf][nf] = __builtin_amdgcn_mfma_f32_16x16x32_bf16(
                        afr[mf], bfr[nf], acc[mf][nf], 0, 0, 0);
        }

        if (it < 7) {
#pragma unroll
            for (int i = 0; i < 4; ++i) {
                int g = tid + i * 256;
                union { __hip_bfloat162 q[4]; int4 pk; } ua, ub;
                ua.q[0] = __float22bfloat162_rn(make_float2(ra[i][0].x, ra[i][0].y));
                ua.q[1] = __float22bfloat162_rn(make_float2(ra[i][0].z, ra[i][0].w));
                ua.q[2] = __float22bfloat162_rn(make_float2(ra[i][1].x, ra[i][1].y));
                ua.q[3] = __float22bfloat162_rn(make_float2(ra[i][1].z, ra[i][1].w));
                ub.q[0] = __float22bfloat162_rn(make_float2(rb[i][0].x, rb[i][0].y));
                ub.q[1] = __float22bfloat162_rn(make_float2(rb[i][0].z, rb[i][0].w));
                ub.q[2] = __float22bfloat162_rn(make_float2(rb[i][1].x, rb[i][1].y));
                ub.q[3] = __float22bfloat162_rn(make_float2(rb[i][1].z, rb[i][1].w));
                *(int4*)&lds[p ^ 1][g * 8]        = ua.pk;
                *(int4*)&lds[p ^ 1][8192 + g * 8] = ub.pk;
            }
            if (it < 6) {
                const int kb2 = (it + 2) * 64;
#pragma unroll
                for (int i = 0; i < 4; ++i) {
                    const float* sa = &X [(size_t)(rbase + srow[i]) * 512 + kb2 + skof[i]];
                    const float* sb = &W1[(size_t)(nbase + srow[i]) * 512 + kb2 + skof[i]];
                    ra[i][0] = *(const float4*)sa;  ra[i][1] = *(const float4*)(sa + 4);
                    rb[i][0] = *(const float4*)sb;  rb[i][1] = *(const float4*)(sb + 4);
                }
            }
        }

        {
            bf16x8 afr[4], bfr[4];
#pragma unroll
            for (int mf = 0; mf < 4; ++mf)
                afr[mf] = *(const bf16x8*)&lds[p][((8 + wm * 4 + mf) * 64 + lane) * 8];
#pragma unroll
            for (int nf = 0; nf < 4; ++nf)
                bfr[nf] = *(const bf16x8*)&lds[p][8192 + ((8 + wn * 4 + nf) * 64 + lane) * 8];
#pragma unroll
            for (int mf = 0; mf < 4; ++mf)
#pragma unroll
                for (int nf = 0; nf < 4; ++nf)
                    acc[mf][nf] = __builtin_amdgcn_mfma_f32_16x16x32_bf16(
                        afr[mf], bfr[nf], acc[mf][nf], 0, 0, 0);
        }

        p ^= 1;
    }

    float bc[4];
#pragma unroll
    for (int nf = 0; nf < 4; ++nf)
        bc[nf] = b1[nbase + wn * 64 + nf * 16 + (lane & 15)];
#pragma unroll
    for (int mf = 0; mf < 4; ++mf) {
#pragma unroll
        for (int nf = 0; nf < 4; ++nf) {
#pragma unroll
            for (int r = 0; r < 4; ++r) {
                int m = rbase + wm * 64 + mf * 16 + ((lane >> 4) << 2) + r;
                int n = nbase + wn * 64 + nf * 16 + (lane & 15);
                P[(size_t)m * 512 + n] = acc[mf][nf][r] + bc[nf];
            }
        }
    }
}

// ---------------------------------------------------------------------------
// Kernel 2: per-batch Gram via MFMA (unchanged — verified rounds 8-13)
// ---------------------------------------------------------------------------
__global__ __launch_bounds__(256) void gram_kernel(
    const float* __restrict__ X,    // [T][B][NX]
    float* __restrict__ Gt)         // [B][64][64]
{
    const int b    = blockIdx.x;
    const int tid  = threadIdx.x;
    const int lane = tid & 63;
    const int w    = tid >> 6;

    __shared__ unsigned short xs[4096 * 8];   // 64 KB, fragment order

#pragma unroll
    for (int i = 0; i < 16; ++i) {
        int g   = tid + i * 256;
        int ks  = g >> 8;
        int ms  = (g >> 6) & 3;
        int l   = g & 63;
        int row = ms * 16 + (l & 15);
        int k   = ks * 32 + (l >> 4) * 8;
        const float* src = &X[(size_t)row * (BATCH * NX) + (size_t)b * NX + k];
        float4 v0 = *(const float4*)src;
        float4 v1 = *(const float4*)(src + 4);
        union { __hip_bfloat162 q[4]; int4 pk; } u;
        u.q[0] = __float22bfloat162_rn(make_float2(v0.x, v0.y));
        u.q[1] = __float22bfloat162_rn(make_float2(v0.z, v0.w));
        u.q[2] = __float22bfloat162_rn(make_float2(v1.x, v1.y));
        u.q[3] = __float22bfloat162_rn(make_float2(v1.z, v1.w));
        *(int4*)&xs[g * 8] = u.pk;
    }
    __syncthreads();

    f32x4 acc[4] = {};
#pragma unroll
    for (int ks = 0; ks < 16; ++ks) {
        bf16x8 afr = *(const bf16x8*)&xs[((ks * 4 + w) * 64 + lane) * 8];
#pragma unroll
        for (int nf = 0; nf < 4; ++nf) {
            bf16x8 bfr = *(const bf16x8*)&xs[((ks * 4 + nf) * 64 + lane) * 8];
            acc[nf] = __builtin_amdgcn_mfma_f32_16x16x32_bf16(afr, bfr, acc[nf], 0, 0, 0);
        }
    }

#pragma unroll
    for (int nf = 0; nf < 4; ++nf) {
#pragma unroll
        for (int r = 0; r < 4; ++r) {
            int mrow = w * 16 + ((lane >> 4) << 2) + r;
            int ncol = nf * 16 + (lane & 15);
            Gt[((size_t)b * 64 + mrow) * 64 + ncol] = acc[nf][r];
        }
    }
}

// ---------------------------------------------------------------------------
// 64-lane sum via DPP; result valid in lane 63. (HW-verified rounds 4-13)
// ---------------------------------------------------------------------------
__device__ __forceinline__ float dpp_sum64(float v) {
    v += __int_as_float(__builtin_amdgcn_update_dpp(0, __float_as_int(v), 0x111, 0xf, 0xf, true)); // row_shr:1
    v += __int_as_float(__builtin_amdgcn_update_dpp(0, __float_as_int(v), 0x112, 0xf, 0xf, true)); // row_shr:2
    v += __int_as_float(__builtin_amdgcn_update_dpp(0, __float_as_int(v), 0x114, 0xf, 0xf, true)); // row_shr:4
    v += __int_as_float(__builtin_amdgcn_update_dpp(0, __float_as_int(v), 0x118, 0xf, 0xf, true)); // row_shr:8
    v += __int_as_float(__builtin_amdgcn_update_dpp(0, __float_as_int(v), 0x142, 0xf, 0xf, true)); // row_bcast:15
    v += __int_as_float(__builtin_amdgcn_update_dpp(0, __float_as_int(v), 0x143, 0xf, 0xf, true)); // row_bcast:31
    return v;
}

// ---------------------------------------------------------------------------
// Kernel 3: scan v6 — r12 skeleton with LGKM-ONLY barriers.
//   __syncthreads() emits s_waitcnt vmcnt(0) lgkmcnt(0) + s_barrier; the
//   vmcnt(0) stalls all 8 waves on the youngest outH store EVERY step and
//   drains the chunk-start pvreg loads at the C barrier. Scan needs only
//   LDS ordering across threads: all global traffic is same-thread per
//   address (thread h reads P column h before overwriting it as outH column
//   h; pvreg loads are same-thread, ordered by their own vmcnt at use).
//   -> raw "s_waitcnt lgkmcnt(0); s_barrier" everywhere (m201 pattern).
//   Everything else identical to r12 (verified 47.5 us, absmax bf16 floor).
// ---------------------------------------------------------------------------
__global__ __launch_bounds__(512, 1) void scan_kernel(
    const float* __restrict__ P,    // [T][B][NH]  (== outH, aliased)
    const float* __restrict__ Gt,   // [B][64][64]
    const float* __restrict__ w2,   // [NH][2]
    const float* __restrict__ b2,   // [2]
    const float* __restrict__ w21,  // [NH][2]
    const float* __restrict__ lamp,
    const float* __restrict__ etap,
    float* __restrict__ outH,       // [T][B][NH]
    float* __restrict__ outY)       // [T][B][2]
{
    const int b = blockIdx.x;
    const int h = threadIdx.x;

    __shared__ float Hs[64][512];   // 128 KB history; col h private to thread h
    __shared__ float C[16][64];     // per-chunk coefficient matrix
    __shared__ float lam_pow[64];
    __shared__ float red[2][16];

    const float eta = etap[0];
    const float lam = fminf(lamp[0], 1.0f);
    const float2 w21v = *(const float2*)&w21[2 * h];
    const float2 w2v  = *(const float2*)&w2[2 * h];
    const float b20 = b2[0], b21 = b2[1];
    const float* gb  = Gt + (size_t)b * 4096;
    const float* Pb  = P + (size_t)b * NH + h;
    float*       oHb = outH + (size_t)b * NH + h;

    if (h < 64)
        lam_pow[h] = (h == 0) ? 1.0f : exp2f((float)h * log2f(lam));
    BARRIER_LGKM();   // order lam_pow writes before chunk-0 C-build reads

#pragma unroll 1
    for (int c = 0; c < 4; ++c) {
        const int t0 = c * 16;

#pragma unroll
        for (int e = h; e < 1024; e += 512) {
            int tt = e >> 6, s = e & 63;
            int t  = t0 + tt;
            float cv = 0.f;
            if (s < t) cv = eta * lam_pow[t - 1 - s] * gb[t * 64 + s];
            C[tt][s] = cv;
        }

        float pvreg[16];
#pragma unroll
        for (int tt = 0; tt < 16; ++tt)
            pvreg[tt] = Pb[(size_t)(t0 + tt) * (BATCH * NH)];

        BARRIER_LGKM();   // C visible; pvreg loads stay in flight under macc

        float macc[16] = {};
        for (int s4 = 0; s4 < t0; s4 += 4) {
            float hsv0 = Hs[s4 + 0][h];
            float hsv1 = Hs[s4 + 1][h];
            float hsv2 = Hs[s4 + 2][h];
            float hsv3 = Hs[s4 + 3][h];
#pragma unroll
            for (int tt = 0; tt < 16; ++tt) {
                float4 cf = *(const float4*)&C[tt][s4];
                macc[tt] = fmaf(cf.x, hsv0, macc[tt]);
                macc[tt] = fmaf(cf.y, hsv1, macc[tt]);
                macc[tt] = fmaf(cf.z, hsv2, macc[tt]);
                macc[tt] = fmaf(cf.w, hsv3, macc[tt]);
            }
        }

        float hcur[16];
        float partial = pvreg[0] + macc[0];
#pragma unroll
        for (int tt = 0; tt < 16; ++tt) {
            const int t = t0 + tt;

            float a2x, a2y;
            if (t == 0) {
                a2x = 0.f; a2y = 0.f;
            } else {
                const int pr = (t - 1) & 1;
                float4 r0 = *(const float4*)&red[pr][0];
                float4 r1 = *(const float4*)&red[pr][4];
                float4 r2 = *(const float4*)&red[pr][8];
                float4 r3 = *(const float4*)&red[pr][12];
                float s0 = b20 + ((r0.x + r0.z) + (r1.x + r1.z)) + ((r2.x + r2.z) + (r3.x + r3.z));
                float s1 = b21 + ((r0.y + r0.w) + (r1.y + r1.w)) + ((r2.y + r2.w) + (r3.y + r3.w));
                a2x = s0; a2y = s1;
                if (h == 0) {
                    outY[((size_t)(t - 1) * BATCH + b) * 2 + 0] = 1.0f / (1.0f + __expf(-s0));
                    outY[((size_t)(t - 1) * BATCH + b) * 2 + 1] = 1.0f / (1.0f + __expf(-s1));
                }
            }

            float a1 = partial + w21v.x * a2x + w21v.y * a2y;
            float hv = 1.0f / (1.0f + __expf(-a1));
            hcur[tt] = hv;
            Hs[t][h] = hv;
            oHb[(size_t)t * (BATCH * NH)] = hv;

            float p0 = dpp_sum64(hv * w2v.x);
            float p1 = dpp_sum64(hv * w2v.y);
            if ((h & 63) == 63) {
                red[t & 1][(h >> 6) * 2]     = p0;
                red[t & 1][(h >> 6) * 2 + 1] = p1;
            }

            if (tt < 15) {
                partial = pvreg[tt + 1] + macc[tt + 1];
#pragma unroll
                for (int j = 0; j <= tt; ++j)
                    partial = fmaf(C[tt + 1][t0 + j], hcur[j], partial);
            }

            BARRIER_LGKM();   // LDS ordering only; outH stores never drained here
        }
    }

    {
        float4 r0 = *(const float4*)&red[63 & 1][0];
        float4 r1 = *(const float4*)&red[63 & 1][4];
        float4 r2 = *(const float4*)&red[63 & 1][8];
        float4 r3 = *(const float4*)&red[63 & 1][12];
        float s0 = b20 + ((r0.x + r0.z) + (r1.x + r1.z)) + ((r2.x + r2.z) + (r3.x + r3.z));
        float s1 = b21 + ((r0.y + r0.w) + (r1.y + r1.w)) + ((r2.y + r2.w) + (r3.y + r3.w));
        if (h == 0) {
            outY[((size_t)63 * BATCH + b) * 2 + 0] = 1.0f / (1.0f + __expf(-s0));
            outY[((size_t)63 * BATCH + b) * 2 + 1] = 1.0f / (1.0f + __expf(-s1));
        }
    }
}

// ---------------------------------------------------------------------------
extern "C" void kernel_launch(void* const* d_in, const int* in_sizes, int n_in,
                              void* d_out, int out_size, void* d_ws, size_t ws_size,
                              hipStream_t stream) {
    const float* x   = (const float*)d_in[0];
    const float* w1  = (const float*)d_in[1];
    const float* b1  = (const float*)d_in[2];
    const float* w2  = (const float*)d_in[3];
    const float* b2  = (const float*)d_in[4];
    const float* w21 = (const float*)d_in[5];
    const float* lam = (const float*)d_in[6];
    const float* eta = (const float*)d_in[7];

    float* outH = (float*)d_out;                       // [64*256*512], doubles as P
    float* outY = outH + (size_t)T_STEPS * BATCH * NH; // [64*256*2]
    float* Gt   = (float*)d_ws;                        // [256*64*64] = 4 MB

    gemm_bf16_kernel<<<dim3(128, 4), 256, 0, stream>>>(x, w1, b1, outH);
    gram_kernel<<<256, 256, 0, stream>>>(x, Gt);
    scan_kernel<<<256, 512, 0, stream>>>(outH, Gt, w2, b2, w21, lam, eta, outH, outY);
}

// Round 15
// 83.390 us; speedup vs baseline: 1.0727x; 1.0727x over previous
//
#include <hip/hip_runtime.h>
#include <hip/hip_bf16.h>
#include <math.h>

#define T_STEPS 64
#define BATCH   256
#define NX      512
#define NH      512

typedef short bf16x8 __attribute__((ext_vector_type(8)));
typedef float f32x4  __attribute__((ext_vector_type(4)));

// ---------------------------------------------------------------------------
// 64-lane sum via DPP; result valid in lane 63. (HW-verified rounds 4-14)
// ---------------------------------------------------------------------------
__device__ __forceinline__ float dpp_sum64(float v) {
    v += __int_as_float(__builtin_amdgcn_update_dpp(0, __float_as_int(v), 0x111, 0xf, 0xf, true)); // row_shr:1
    v += __int_as_float(__builtin_amdgcn_update_dpp(0, __float_as_int(v), 0x112, 0xf, 0xf, true)); // row_shr:2
    v += __int_as_float(__builtin_amdgcn_update_dpp(0, __float_as_int(v), 0x114, 0xf, 0xf, true)); // row_shr:4
    v += __int_as_float(__builtin_amdgcn_update_dpp(0, __float_as_int(v), 0x118, 0xf, 0xf, true)); // row_shr:8
    v += __int_as_float(__builtin_amdgcn_update_dpp(0, __float_as_int(v), 0x142, 0xf, 0xf, true)); // row_bcast:15
    v += __int_as_float(__builtin_amdgcn_update_dpp(0, __float_as_int(v), 0x143, 0xf, 0xf, true)); // row_bcast:31
    return v;
}

__device__ __forceinline__ __hip_bfloat162 cvt2(float a, float b) {
    return __float22bfloat162_rn(make_float2(a, b));
}

// ---------------------------------------------------------------------------
// FUSED kernel: one block per batch (256 blocks x 512 threads).
//   Phase 1: stage X_b -> LDS bf16 fragments xs (64 KB; aliases Hs[0..31],
//            dead before scan's first Hs write).
//   Phase 2: Gram G = X_b X_b^T via MFMA (both operands from xs, r8-verified);
//            G -> LDS Gl (replaces the global Gt workspace).
//   Phase 3: P-GEMM: wave w computes P[t=0..63][h in w*64..w*64+64):
//            A-frags from xs, B-frags streamed from W1 global (L2-resident,
//            shared by 32 blocks/XCD) with one-ks-ahead register prefetch;
//            verified epilogue (+b1) stores P to outH global.
//            __syncthreads (vmcnt drain) publishes P block-wide via L2.
//   Phase 4: scan — round-12 code VERBATIM (measured 47.5 us), except
//            C-build reads Gl (LDS) instead of global Gt.
//   LDS: Hs 128K (first 64K doubles as xs) + Gl 16.9K + C 4K + misc ~ 149.5K
//        -> 1 block/CU, same occupancy as the standalone scan.
// ---------------------------------------------------------------------------
__global__ __launch_bounds__(512, 1) void fused_kernel(
    const float* __restrict__ x,    // [T][B][NX]
    const float* __restrict__ w1,   // [NH][NX]
    const float* __restrict__ b1,   // [NH]
    const float* __restrict__ w2,   // [NH][2]
    const float* __restrict__ b2,   // [2]
    const float* __restrict__ w21,  // [NH][2]
    const float* __restrict__ lamp,
    const float* __restrict__ etap,
    float* __restrict__ outH,       // [T][B][NH]; also holds P transiently
    float* __restrict__ outY)       // [T][B][2]
{
    const int b    = blockIdx.x;
    const int h    = threadIdx.x;   // scan identity; also tid
    const int lane = h & 63;
    const int wv   = h >> 6;

    __shared__ float Hs[64][512];   // 128 KB; Hs[0..31] doubles as xs in setup
    __shared__ float Gl[64][66];    // Gram (padded rows)
    __shared__ float C[16][64];
    __shared__ float lam_pow[64];
    __shared__ float red[2][16];

    unsigned short* xs = (unsigned short*)&Hs[0][0];   // 4096 groups * 8 bf16

    const float eta = etap[0];
    const float lam = fminf(lamp[0], 1.0f);
    const float2 w21v = *(const float2*)&w21[2 * h];
    const float2 w2v  = *(const float2*)&w2[2 * h];
    const float b20 = b2[0], b21 = b2[1];
    const float* Pb  = outH + (size_t)b * NH + h;      // P lives in outH
    float*       oHb = outH + (size_t)b * NH + h;

    // ---- phase 1: stage X_b as bf16 fragments --------------------------
    if (h < 64)
        lam_pow[h] = (h == 0) ? 1.0f : exp2f((float)h * log2f(lam));
#pragma unroll
    for (int i = 0; i < 8; ++i) {
        int g   = h + i * 512;            // 0..4095
        int ks  = g >> 8;
        int ms  = (g >> 6) & 3;
        int l   = g & 63;
        int row = ms * 16 + (l & 15);     // t
        int k   = ks * 32 + (l >> 4) * 8;
        const float* src = &x[((size_t)row * BATCH + b) * NX + k];
        float4 v0 = *(const float4*)src;
        float4 v1 = *(const float4*)(src + 4);
        union { __hip_bfloat162 q[4]; int4 pk; } u;
        u.q[0] = cvt2(v0.x, v0.y); u.q[1] = cvt2(v0.z, v0.w);
        u.q[2] = cvt2(v1.x, v1.y); u.q[3] = cvt2(v1.z, v1.w);
        *(int4*)&xs[g * 8] = u.pk;
    }
    __syncthreads();   // xs + lam_pow visible

    // ---- phase 2: Gram -> Gl (2 tiles per wave) ------------------------
    {
        const int mt_g = wv >> 1;
#pragma unroll
        for (int j = 0; j < 2; ++j) {
            const int nt_g = (wv & 1) * 2 + j;
            f32x4 gacc = {};
#pragma unroll
            for (int ks = 0; ks < 16; ++ks) {
                bf16x8 afr = *(const bf16x8*)&xs[((ks * 4 + mt_g) * 64 + lane) * 8];
                bf16x8 bfr = *(const bf16x8*)&xs[((ks * 4 + nt_g) * 64 + lane) * 8];
                gacc = __builtin_amdgcn_mfma_f32_16x16x32_bf16(afr, bfr, gacc, 0, 0, 0);
            }
#pragma unroll
            for (int r = 0; r < 4; ++r)
                Gl[mt_g * 16 + ((lane >> 4) << 2) + r][nt_g * 16 + (lane & 15)] = gacc[r];
        }
    }

    // ---- phase 3: P-GEMM (A from xs, B streamed from W1) ---------------
    {
        f32x4 pacc[4][4] = {};          // [mt][nf]
        const int kla = (lane >> 4) * 8;
        int wrow[4];
#pragma unroll
        for (int nf = 0; nf < 4; ++nf)
            wrow[nf] = wv * 64 + nf * 16 + (lane & 15);

        float4 wp[4][2];
#pragma unroll
        for (int nf = 0; nf < 4; ++nf) {
            const float* s = &w1[(size_t)wrow[nf] * 512 + kla];
            wp[nf][0] = *(const float4*)s;
            wp[nf][1] = *(const float4*)(s + 4);
        }

#pragma unroll
        for (int ks = 0; ks < 16; ++ks) {
            bf16x8 afr[4];
#pragma unroll
            for (int mt = 0; mt < 4; ++mt)
                afr[mt] = *(const bf16x8*)&xs[((ks * 4 + mt) * 64 + lane) * 8];

            bf16x8 bfr[4];
#pragma unroll
            for (int nf = 0; nf < 4; ++nf) {
                union { __hip_bfloat162 q[4]; bf16x8 v; } u;
                u.q[0] = cvt2(wp[nf][0].x, wp[nf][0].y);
                u.q[1] = cvt2(wp[nf][0].z, wp[nf][0].w);
                u.q[2] = cvt2(wp[nf][1].x, wp[nf][1].y);
                u.q[3] = cvt2(wp[nf][1].z, wp[nf][1].w);
                bfr[nf] = u.v;
            }
            if (ks < 15) {
#pragma unroll
                for (int nf = 0; nf < 4; ++nf) {
                    const float* s = &w1[(size_t)wrow[nf] * 512 + (ks + 1) * 32 + kla];
                    wp[nf][0] = *(const float4*)s;
                    wp[nf][1] = *(const float4*)(s + 4);
                }
            }
#pragma unroll
            for (int mt = 0; mt < 4; ++mt)
#pragma unroll
                for (int nf = 0; nf < 4; ++nf)
                    pacc[mt][nf] = __builtin_amdgcn_mfma_f32_16x16x32_bf16(
                        afr[mt], bfr[nf], pacc[mt][nf], 0, 0, 0);
        }

        // epilogue: +b1, store P to global (outH region)
        float bc[4];
#pragma unroll
        for (int nf = 0; nf < 4; ++nf)
            bc[nf] = b1[wv * 64 + nf * 16 + (lane & 15)];
#pragma unroll
        for (int mt = 0; mt < 4; ++mt) {
#pragma unroll
            for (int nf = 0; nf < 4; ++nf) {
#pragma unroll
                for (int r = 0; r < 4; ++r) {
                    int t = mt * 16 + ((lane >> 4) << 2) + r;
                    int n = wv * 64 + nf * 16 + (lane & 15);
                    outH[(size_t)t * (BATCH * NH) + (size_t)b * NH + n] =
                        pacc[mt][nf][r] + bc[nf];
                }
            }
        }
    }
    __syncthreads();   // drains vmcnt: P visible block-wide; xs now dead

    // ---- phase 4: scan (round-12 code, C-build from Gl) ----------------
#pragma unroll 1
    for (int c = 0; c < 4; ++c) {
        const int t0 = c * 16;

#pragma unroll
        for (int e = h; e < 1024; e += 512) {
            int tt = e >> 6, s = e & 63;
            int t  = t0 + tt;
            float cv = 0.f;
            if (s < t) cv = eta * lam_pow[t - 1 - s] * Gl[t][s];
            C[tt][s] = cv;
        }

        float pvreg[16];
#pragma unroll
        for (int tt = 0; tt < 16; ++tt)
            pvreg[tt] = Pb[(size_t)(t0 + tt) * (BATCH * NH)];

        __syncthreads();   // C visible; orders prev chunk's last red write

        float macc[16] = {};
        for (int s4 = 0; s4 < t0; s4 += 4) {
            float hsv0 = Hs[s4 + 0][h];
            float hsv1 = Hs[s4 + 1][h];
            float hsv2 = Hs[s4 + 2][h];
            float hsv3 = Hs[s4 + 3][h];
#pragma unroll
            for (int tt = 0; tt < 16; ++tt) {
                float4 cf = *(const float4*)&C[tt][s4];
                macc[tt] = fmaf(cf.x, hsv0, macc[tt]);
                macc[tt] = fmaf(cf.y, hsv1, macc[tt]);
                macc[tt] = fmaf(cf.z, hsv2, macc[tt]);
                macc[tt] = fmaf(cf.w, hsv3, macc[tt]);
            }
        }

        float hcur[16];
        float partial = pvreg[0] + macc[0];
#pragma unroll
        for (int tt = 0; tt < 16; ++tt) {
            const int t = t0 + tt;

            float a2x, a2y;
            if (t == 0) {
                a2x = 0.f; a2y = 0.f;
            } else {
                const int pr = (t - 1) & 1;
                float4 r0 = *(const float4*)&red[pr][0];
                float4 r1 = *(const float4*)&red[pr][4];
                float4 r2 = *(const float4*)&red[pr][8];
                float4 r3 = *(const float4*)&red[pr][12];
                float s0 = b20 + ((r0.x + r0.z) + (r1.x + r1.z)) + ((r2.x + r2.z) + (r3.x + r3.z));
                float s1 = b21 + ((r0.y + r0.w) + (r1.y + r1.w)) + ((r2.y + r2.w) + (r3.y + r3.w));
                a2x = s0; a2y = s1;
                if (h == 0) {
                    outY[((size_t)(t - 1) * BATCH + b) * 2 + 0] = 1.0f / (1.0f + __expf(-s0));
                    outY[((size_t)(t - 1) * BATCH + b) * 2 + 1] = 1.0f / (1.0f + __expf(-s1));
                }
            }

            float a1 = partial + w21v.x * a2x + w21v.y * a2y;
            float hv = 1.0f / (1.0f + __expf(-a1));
            hcur[tt] = hv;
            Hs[t][h] = hv;
            oHb[(size_t)t * (BATCH * NH)] = hv;

            float p0 = dpp_sum64(hv * w2v.x);
            float p1 = dpp_sum64(hv * w2v.y);
            if ((h & 63) == 63) {
                red[t & 1][(h >> 6) * 2]     = p0;
                red[t & 1][(h >> 6) * 2 + 1] = p1;
            }

            if (tt < 15) {
                partial = pvreg[tt + 1] + macc[tt + 1];
#pragma unroll
                for (int j = 0; j <= tt; ++j)
                    partial = fmaf(C[tt + 1][t0 + j], hcur[j], partial);
            }

            __syncthreads();
        }
    }

    {
        float4 r0 = *(const float4*)&red[63 & 1][0];
        float4 r1 = *(const float4*)&red[63 & 1][4];
        float4 r2 = *(const float4*)&red[63 & 1][8];
        float4 r3 = *(const float4*)&red[63 & 1][12];
        float s0 = b20 + ((r0.x + r0.z) + (r1.x + r1.z)) + ((r2.x + r2.z) + (r3.x + r3.z));
        float s1 = b21 + ((r0.y + r0.w) + (r1.y + r1.w)) + ((r2.y + r2.w) + (r3.y + r3.w));
        if (h == 0) {
            outY[((size_t)63 * BATCH + b) * 2 + 0] = 1.0f / (1.0f + __expf(-s0));
            outY[((size_t)63 * BATCH + b) * 2 + 1] = 1.0f / (1.0f + __expf(-s1));
        }
    }
}

// ---------------------------------------------------------------------------
extern "C" void kernel_launch(void* const* d_in, const int* in_sizes, int n_in,
                              void* d_out, int out_size, void* d_ws, size_t ws_size,
                              hipStream_t stream) {
    const float* x   = (const float*)d_in[0];
    const float* w1  = (const float*)d_in[1];
    const float* b1  = (const float*)d_in[2];
    const float* w2  = (const float*)d_in[3];
    const float* b2  = (const float*)d_in[4];
    const float* w21 = (const float*)d_in[5];
    const float* lam = (const float*)d_in[6];
    const float* eta = (const float*)d_in[7];

    float* outH = (float*)d_out;                       // [64*256*512], doubles as P
    float* outY = outH + (size_t)T_STEPS * BATCH * NH; // [64*256*2]

    fused_kernel<<<256, 512, 0, stream>>>(x, w1, b1, w2, b2, w21, lam, eta, outH, outY);
}

// Round 16
// 66.046 us; speedup vs baseline: 1.3544x; 1.2626x over previous
//
#include <hip/hip_runtime.h>
#include <hip/hip_bf16.h>
#include <math.h>

#define T_STEPS 64
#define BATCH   256
#define NX      512
#define NH      512

typedef short bf16x8 __attribute__((ext_vector_type(8)));
typedef float f32x4  __attribute__((ext_vector_type(4)));

__device__ __forceinline__ float dpp_sum64(float v) {
    v += __int_as_float(__builtin_amdgcn_update_dpp(0, __float_as_int(v), 0x111, 0xf, 0xf, true)); // row_shr:1
    v += __int_as_float(__builtin_amdgcn_update_dpp(0, __float_as_int(v), 0x112, 0xf, 0xf, true)); // row_shr:2
    v += __int_as_float(__builtin_amdgcn_update_dpp(0, __float_as_int(v), 0x114, 0xf, 0xf, true)); // row_shr:4
    v += __int_as_float(__builtin_amdgcn_update_dpp(0, __float_as_int(v), 0x118, 0xf, 0xf, true)); // row_shr:8
    v += __int_as_float(__builtin_amdgcn_update_dpp(0, __float_as_int(v), 0x142, 0xf, 0xf, true)); // row_bcast:15
    v += __int_as_float(__builtin_amdgcn_update_dpp(0, __float_as_int(v), 0x143, 0xf, 0xf, true)); // row_bcast:31
    return v;
}

__device__ __forceinline__ __hip_bfloat162 cvt2(float a, float b) {
    return __float22bfloat162_rn(make_float2(a, b));
}

// ---------------------------------------------------------------------------
// Prep kernel: W1 f32 -> fragment-ordered bf16 (run ONCE, not per block).
//   Fragment group g = (ks*32 + rb)*64 + ll holds 8 bf16 of W1 row
//   rb*16 + (ll&15), k = ks*32 + (ll>>4)*8  (same convention as xs frags).
//   tid -> (row = tid>>6, oct = tid&63): reads are 32B-contiguous per lane
//   within a row -> fully coalesced.
// ---------------------------------------------------------------------------
__global__ __launch_bounds__(256) void w1_prep_kernel(
    const float* __restrict__ w1, unsigned short* __restrict__ w1f)
{
    int tid = blockIdx.x * 256 + threadIdx.x;   // 0..32767
    int row = tid >> 6;
    int oct = tid & 63;
    const float* s = &w1[(size_t)row * 512 + oct * 8];
    float4 v0 = *(const float4*)s;
    float4 v1 = *(const float4*)(s + 4);
    union { __hip_bfloat162 q[4]; int4 pk; } u;
    u.q[0] = cvt2(v0.x, v0.y); u.q[1] = cvt2(v0.z, v0.w);
    u.q[2] = cvt2(v1.x, v1.y); u.q[3] = cvt2(v1.z, v1.w);
    int g = ((oct >> 2) * 32 + (row >> 4)) * 64 + (row & 15) + 16 * (oct & 3);
    *(int4*)&w1f[(size_t)g * 8] = u.pk;
}

// ---------------------------------------------------------------------------
// FUSED kernel (r15 structure, GEMM phases repaired):
//   Phase 1: X_b -> xs bf16 frags, COALESCED (wave w stages row w+8i; lane =
//            k-oct -> 2KB contiguous per wave-instruction). LDS write banks
//            are wave-disjoint (bank group = row&7 = wv&7).
//   Phase 2: Gram -> Gl via MFMA (unchanged, r8-verified).
//   Phase 3: P-GEMM; B-frags = DIRECT coalesced bf16 loads from w1f (no cvt),
//            2-deep parity prefetch bfp[2][4]; first loads issued before
//            phase 2 so misses fly under Gram MFMAs. Epilogue (verified)
//            stores P to outH; __syncthreads publishes block-wide.
//   Phase 4: scan — round-12 code verbatim (measured floor ~47.5 profiled).
// ---------------------------------------------------------------------------
__global__ __launch_bounds__(512, 1) void fused_kernel(
    const float* __restrict__ x,    // [T][B][NX]
    const unsigned short* __restrict__ w1f,  // fragment-ordered bf16 W1
    const float* __restrict__ b1,   // [NH]
    const float* __restrict__ w2,   // [NH][2]
    const float* __restrict__ b2,   // [2]
    const float* __restrict__ w21,  // [NH][2]
    const float* __restrict__ lamp,
    const float* __restrict__ etap,
    float* __restrict__ outH,       // [T][B][NH]; also holds P transiently
    float* __restrict__ outY)       // [T][B][2]
{
    const int b    = blockIdx.x;
    const int h    = threadIdx.x;
    const int lane = h & 63;
    const int wv   = h >> 6;

    __shared__ float Hs[64][512];   // 128 KB; first 64 KB doubles as xs
    __shared__ float Gl[64][66];
    __shared__ float C[16][64];
    __shared__ float lam_pow[64];
    __shared__ float red[2][16];

    unsigned short* xs = (unsigned short*)&Hs[0][0];

    const float eta = etap[0];
    const float lam = fminf(lamp[0], 1.0f);
    const float2 w21v = *(const float2*)&w21[2 * h];
    const float2 w2v  = *(const float2*)&w2[2 * h];
    const float b20 = b2[0], b21 = b2[1];
    const float* Pb  = outH + (size_t)b * NH + h;
    float*       oHb = outH + (size_t)b * NH + h;

    // ---- phase 1: coalesced X staging -----------------------------------
    if (h < 64)
        lam_pow[h] = (h == 0) ? 1.0f : exp2f((float)h * log2f(lam));
#pragma unroll
    for (int i = 0; i < 8; ++i) {
        int r = wv + i * 8;
        int o = lane;
        const float* src = &x[((size_t)r * BATCH + b) * NX + o * 8];
        float4 v0 = *(const float4*)src;
        float4 v1 = *(const float4*)(src + 4);
        union { __hip_bfloat162 q[4]; int4 pk; } u;
        u.q[0] = cvt2(v0.x, v0.y); u.q[1] = cvt2(v0.z, v0.w);
        u.q[2] = cvt2(v1.x, v1.y); u.q[3] = cvt2(v1.z, v1.w);
        int g = ((o >> 2) * 4 + (r >> 4)) * 64 + (r & 15) + 16 * (o & 3);
        *(int4*)&xs[g * 8] = u.pk;
    }
    __syncthreads();   // xs + lam_pow visible

    // ---- phase 3 prefetch (issued early: misses fly under Gram) ---------
    bf16x8 bfp[2][4];
#pragma unroll
    for (int nf = 0; nf < 4; ++nf)
        bfp[0][nf] = *(const bf16x8*)&w1f[(size_t)((0 * 32 + wv * 4 + nf) * 64 + lane) * 8];

    // ---- phase 2: Gram -> Gl (2 tiles per wave) -------------------------
    {
        const int mt_g = wv >> 1;
#pragma unroll
        for (int j = 0; j < 2; ++j) {
            const int nt_g = (wv & 1) * 2 + j;
            f32x4 gacc = {};
#pragma unroll
            for (int ks = 0; ks < 16; ++ks) {
                bf16x8 afr = *(const bf16x8*)&xs[((ks * 4 + mt_g) * 64 + lane) * 8];
                bf16x8 bfr = *(const bf16x8*)&xs[((ks * 4 + nt_g) * 64 + lane) * 8];
                gacc = __builtin_amdgcn_mfma_f32_16x16x32_bf16(afr, bfr, gacc, 0, 0, 0);
            }
#pragma unroll
            for (int r = 0; r < 4; ++r)
                Gl[mt_g * 16 + ((lane >> 4) << 2) + r][nt_g * 16 + (lane & 15)] = gacc[r];
        }
    }

    // ---- phase 3: P-GEMM (A from xs, B direct bf16 from w1f) ------------
    {
        f32x4 pacc[4][4] = {};
#pragma unroll
        for (int ks = 0; ks < 16; ++ks) {
            if (ks < 15) {
#pragma unroll
                for (int nf = 0; nf < 4; ++nf)
                    bfp[(ks + 1) & 1][nf] = *(const bf16x8*)
                        &w1f[(size_t)(((ks + 1) * 32 + wv * 4 + nf) * 64 + lane) * 8];
            }
            bf16x8 afr[4];
#pragma unroll
            for (int mt = 0; mt < 4; ++mt)
                afr[mt] = *(const bf16x8*)&xs[((ks * 4 + mt) * 64 + lane) * 8];
#pragma unroll
            for (int mt = 0; mt < 4; ++mt)
#pragma unroll
                for (int nf = 0; nf < 4; ++nf)
                    pacc[mt][nf] = __builtin_amdgcn_mfma_f32_16x16x32_bf16(
                        afr[mt], bfp[ks & 1][nf], pacc[mt][nf], 0, 0, 0);
        }

        float bc[4];
#pragma unroll
        for (int nf = 0; nf < 4; ++nf)
            bc[nf] = b1[wv * 64 + nf * 16 + (lane & 15)];
#pragma unroll
        for (int mt = 0; mt < 4; ++mt) {
#pragma unroll
            for (int nf = 0; nf < 4; ++nf) {
#pragma unroll
                for (int r = 0; r < 4; ++r) {
                    int t = mt * 16 + ((lane >> 4) << 2) + r;
                    int n = wv * 64 + nf * 16 + (lane & 15);
                    outH[(size_t)t * (BATCH * NH) + (size_t)b * NH + n] =
                        pacc[mt][nf][r] + bc[nf];
                }
            }
        }
    }
    __syncthreads();   // drains vmcnt: P visible block-wide; xs now dead

    // ---- phase 4: scan (round-12 code, C-build from Gl) -----------------
#pragma unroll 1
    for (int c = 0; c < 4; ++c) {
        const int t0 = c * 16;

#pragma unroll
        for (int e = h; e < 1024; e += 512) {
            int tt = e >> 6, s = e & 63;
            int t  = t0 + tt;
            float cv = 0.f;
            if (s < t) cv = eta * lam_pow[t - 1 - s] * Gl[t][s];
            C[tt][s] = cv;
        }

        float pvreg[16];
#pragma unroll
        for (int tt = 0; tt < 16; ++tt)
            pvreg[tt] = Pb[(size_t)(t0 + tt) * (BATCH * NH)];

        __syncthreads();

        float macc[16] = {};
        for (int s4 = 0; s4 < t0; s4 += 4) {
            float hsv0 = Hs[s4 + 0][h];
            float hsv1 = Hs[s4 + 1][h];
            float hsv2 = Hs[s4 + 2][h];
            float hsv3 = Hs[s4 + 3][h];
#pragma unroll
            for (int tt = 0; tt < 16; ++tt) {
                float4 cf = *(const float4*)&C[tt][s4];
                macc[tt] = fmaf(cf.x, hsv0, macc[tt]);
                macc[tt] = fmaf(cf.y, hsv1, macc[tt]);
                macc[tt] = fmaf(cf.z, hsv2, macc[tt]);
                macc[tt] = fmaf(cf.w, hsv3, macc[tt]);
            }
        }

        float hcur[16];
        float partial = pvreg[0] + macc[0];
#pragma unroll
        for (int tt = 0; tt < 16; ++tt) {
            const int t = t0 + tt;

            float a2x, a2y;
            if (t == 0) {
                a2x = 0.f; a2y = 0.f;
            } else {
                const int pr = (t - 1) & 1;
                float4 r0 = *(const float4*)&red[pr][0];
                float4 r1 = *(const float4*)&red[pr][4];
                float4 r2 = *(const float4*)&red[pr][8];
                float4 r3 = *(const float4*)&red[pr][12];
                float s0 = b20 + ((r0.x + r0.z) + (r1.x + r1.z)) + ((r2.x + r2.z) + (r3.x + r3.z));
                float s1 = b21 + ((r0.y + r0.w) + (r1.y + r1.w)) + ((r2.y + r2.w) + (r3.y + r3.w));
                a2x = s0; a2y = s1;
                if (h == 0) {
                    outY[((size_t)(t - 1) * BATCH + b) * 2 + 0] = 1.0f / (1.0f + __expf(-s0));
                    outY[((size_t)(t - 1) * BATCH + b) * 2 + 1] = 1.0f / (1.0f + __expf(-s1));
                }
            }

            float a1 = partial + w21v.x * a2x + w21v.y * a2y;
            float hv = 1.0f / (1.0f + __expf(-a1));
            hcur[tt] = hv;
            Hs[t][h] = hv;
            oHb[(size_t)t * (BATCH * NH)] = hv;

            float p0 = dpp_sum64(hv * w2v.x);
            float p1 = dpp_sum64(hv * w2v.y);
            if ((h & 63) == 63) {
                red[t & 1][(h >> 6) * 2]     = p0;
                red[t & 1][(h >> 6) * 2 + 1] = p1;
            }

            if (tt < 15) {
                partial = pvreg[tt + 1] + macc[tt + 1];
#pragma unroll
                for (int j = 0; j <= tt; ++j)
                    partial = fmaf(C[tt + 1][t0 + j], hcur[j], partial);
            }

            __syncthreads();
        }
    }

    {
        float4 r0 = *(const float4*)&red[63 & 1][0];
        float4 r1 = *(const float4*)&red[63 & 1][4];
        float4 r2 = *(const float4*)&red[63 & 1][8];
        float4 r3 = *(const float4*)&red[63 & 1][12];
        float s0 = b20 + ((r0.x + r0.z) + (r1.x + r1.z)) + ((r2.x + r2.z) + (r3.x + r3.z));
        float s1 = b21 + ((r0.y + r0.w) + (r1.y + r1.w)) + ((r2.y + r2.w) + (r3.y + r3.w));
        if (h == 0) {
            outY[((size_t)63 * BATCH + b) * 2 + 0] = 1.0f / (1.0f + __expf(-s0));
            outY[((size_t)63 * BATCH + b) * 2 + 1] = 1.0f / (1.0f + __expf(-s1));
        }
    }
}

// ---------------------------------------------------------------------------
extern "C" void kernel_launch(void* const* d_in, const int* in_sizes, int n_in,
                              void* d_out, int out_size, void* d_ws, size_t ws_size,
                              hipStream_t stream) {
    const float* x   = (const float*)d_in[0];
    const float* w1  = (const float*)d_in[1];
    const float* b1  = (const float*)d_in[2];
    const float* w2  = (const float*)d_in[3];
    const float* b2  = (const float*)d_in[4];
    const float* w21 = (const float*)d_in[5];
    const float* lam = (const float*)d_in[6];
    const float* eta = (const float*)d_in[7];

    float* outH = (float*)d_out;                       // [64*256*512], doubles as P
    float* outY = outH + (size_t)T_STEPS * BATCH * NH; // [64*256*2]
    unsigned short* w1f = (unsigned short*)d_ws;       // 512 KB bf16 W1 frags

    w1_prep_kernel<<<128, 256, 0, stream>>>(w1, w1f);
    fused_kernel<<<256, 512, 0, stream>>>(x, w1f, b1, w2, b2, w21, lam, eta, outH, outY);
}

// Round 17
// 62.553 us; speedup vs baseline: 1.4301x; 1.0558x over previous
//
#include <hip/hip_runtime.h>
#include <hip/hip_bf16.h>
#include <math.h>

#define T_STEPS 64
#define BATCH   256
#define NX      512
#define NH      512

typedef short bf16x8 __attribute__((ext_vector_type(8)));
typedef float f32x4  __attribute__((ext_vector_type(4)));

__device__ __forceinline__ float dpp_sum64(float v) {
    v += __int_as_float(__builtin_amdgcn_update_dpp(0, __float_as_int(v), 0x111, 0xf, 0xf, true)); // row_shr:1
    v += __int_as_float(__builtin_amdgcn_update_dpp(0, __float_as_int(v), 0x112, 0xf, 0xf, true)); // row_shr:2
    v += __int_as_float(__builtin_amdgcn_update_dpp(0, __float_as_int(v), 0x114, 0xf, 0xf, true)); // row_shr:4
    v += __int_as_float(__builtin_amdgcn_update_dpp(0, __float_as_int(v), 0x118, 0xf, 0xf, true)); // row_shr:8
    v += __int_as_float(__builtin_amdgcn_update_dpp(0, __float_as_int(v), 0x142, 0xf, 0xf, true)); // row_bcast:15
    v += __int_as_float(__builtin_amdgcn_update_dpp(0, __float_as_int(v), 0x143, 0xf, 0xf, true)); // row_bcast:31
    return v;
}

__device__ __forceinline__ __hip_bfloat162 cvt2(float a, float b) {
    return __float22bfloat162_rn(make_float2(a, b));
}

// ---------------------------------------------------------------------------
// Prep kernel: W1 f32 -> fragment-ordered bf16 (unchanged — verified r16)
// ---------------------------------------------------------------------------
__global__ __launch_bounds__(256) void w1_prep_kernel(
    const float* __restrict__ w1, unsigned short* __restrict__ w1f)
{
    int tid = blockIdx.x * 256 + threadIdx.x;   // 0..32767
    int row = tid >> 6;
    int oct = tid & 63;
    const float* s = &w1[(size_t)row * 512 + oct * 8];
    float4 v0 = *(const float4*)s;
    float4 v1 = *(const float4*)(s + 4);
    union { __hip_bfloat162 q[4]; int4 pk; } u;
    u.q[0] = cvt2(v0.x, v0.y); u.q[1] = cvt2(v0.z, v0.w);
    u.q[2] = cvt2(v1.x, v1.y); u.q[3] = cvt2(v1.z, v1.w);
    int g = ((oct >> 2) * 32 + (row >> 4)) * 64 + (row & 15) + 16 * (oct & 3);
    *(int4*)&w1f[(size_t)g * 8] = u.pk;
}

// ---------------------------------------------------------------------------
// FUSED kernel (r16 + P-in-LDS):
//   Phase 3's P no longer round-trips through HBM. Epilogue writes P+b1 into
//   Hs[t][n] (LDS). Aliasing discipline: at scan chunk c, Hs rows < t0 hold
//   h-history, rows >= t0 still hold P; chunk-start pvreg reads row t0+tt
//   BEFORE step tt overwrites it; existing per-step barriers give ordering.
//   An extra barrier before the epilogue protects the xs alias (rows 0..31).
//   Deletes: 33 MB P store + its vmcnt drain + 33 MB P re-read.
// ---------------------------------------------------------------------------
__global__ __launch_bounds__(512, 1) void fused_kernel(
    const float* __restrict__ x,    // [T][B][NX]
    const unsigned short* __restrict__ w1f,  // fragment-ordered bf16 W1
    const float* __restrict__ b1,   // [NH]
    const float* __restrict__ w2,   // [NH][2]
    const float* __restrict__ b2,   // [2]
    const float* __restrict__ w21,  // [NH][2]
    const float* __restrict__ lamp,
    const float* __restrict__ etap,
    float* __restrict__ outH,       // [T][B][NH]
    float* __restrict__ outY)       // [T][B][2]
{
    const int b    = blockIdx.x;
    const int h    = threadIdx.x;
    const int lane = h & 63;
    const int wv   = h >> 6;

    __shared__ float Hs[64][512];   // 128 KB; rows<t hold h, rows>=t hold P;
                                    // first 64 KB doubles as xs during setup
    __shared__ float Gl[64][66];
    __shared__ float C[16][64];
    __shared__ float lam_pow[64];
    __shared__ float red[2][16];

    unsigned short* xs = (unsigned short*)&Hs[0][0];

    const float eta = etap[0];
    const float lam = fminf(lamp[0], 1.0f);
    const float2 w21v = *(const float2*)&w21[2 * h];
    const float2 w2v  = *(const float2*)&w2[2 * h];
    const float b20 = b2[0], b21 = b2[1];
    float* oHb = outH + (size_t)b * NH + h;

    // ---- phase 1: coalesced X staging -----------------------------------
    if (h < 64)
        lam_pow[h] = (h == 0) ? 1.0f : exp2f((float)h * log2f(lam));
#pragma unroll
    for (int i = 0; i < 8; ++i) {
        int r = wv + i * 8;
        int o = lane;
        const float* src = &x[((size_t)r * BATCH + b) * NX + o * 8];
        float4 v0 = *(const float4*)src;
        float4 v1 = *(const float4*)(src + 4);
        union { __hip_bfloat162 q[4]; int4 pk; } u;
        u.q[0] = cvt2(v0.x, v0.y); u.q[1] = cvt2(v0.z, v0.w);
        u.q[2] = cvt2(v1.x, v1.y); u.q[3] = cvt2(v1.z, v1.w);
        int g = ((o >> 2) * 4 + (r >> 4)) * 64 + (r & 15) + 16 * (o & 3);
        *(int4*)&xs[g * 8] = u.pk;
    }
    __syncthreads();   // xs + lam_pow visible

    // ---- phase 3 prefetch (misses fly under Gram) -----------------------
    bf16x8 bfp[2][4];
#pragma unroll
    for (int nf = 0; nf < 4; ++nf)
        bfp[0][nf] = *(const bf16x8*)&w1f[(size_t)((wv * 4 + nf) * 64 + lane) * 8];

    // ---- phase 2: Gram -> Gl (2 tiles per wave) -------------------------
    {
        const int mt_g = wv >> 1;
#pragma unroll
        for (int j = 0; j < 2; ++j) {
            const int nt_g = (wv & 1) * 2 + j;
            f32x4 gacc = {};
#pragma unroll
            for (int ks = 0; ks < 16; ++ks) {
                bf16x8 afr = *(const bf16x8*)&xs[((ks * 4 + mt_g) * 64 + lane) * 8];
                bf16x8 bfr = *(const bf16x8*)&xs[((ks * 4 + nt_g) * 64 + lane) * 8];
                gacc = __builtin_amdgcn_mfma_f32_16x16x32_bf16(afr, bfr, gacc, 0, 0, 0);
            }
#pragma unroll
            for (int r = 0; r < 4; ++r)
                Gl[mt_g * 16 + ((lane >> 4) << 2) + r][nt_g * 16 + (lane & 15)] = gacc[r];
        }
    }

    // ---- phase 3: P-GEMM (A from xs, B direct bf16 from w1f) ------------
    {
        f32x4 pacc[4][4] = {};
#pragma unroll
        for (int ks = 0; ks < 16; ++ks) {
            if (ks < 15) {
#pragma unroll
                for (int nf = 0; nf < 4; ++nf)
                    bfp[(ks + 1) & 1][nf] = *(const bf16x8*)
                        &w1f[(size_t)(((ks + 1) * 32 + wv * 4 + nf) * 64 + lane) * 8];
            }
            bf16x8 afr[4];
#pragma unroll
            for (int mt = 0; mt < 4; ++mt)
                afr[mt] = *(const bf16x8*)&xs[((ks * 4 + mt) * 64 + lane) * 8];
#pragma unroll
            for (int mt = 0; mt < 4; ++mt)
#pragma unroll
                for (int nf = 0; nf < 4; ++nf)
                    pacc[mt][nf] = __builtin_amdgcn_mfma_f32_16x16x32_bf16(
                        afr[mt], bfp[ks & 1][nf], pacc[mt][nf], 0, 0, 0);
        }

        __syncthreads();   // ALL xs reads complete before P overwrites rows 0..31

        // epilogue: +b1, write P into Hs (LDS) — no global round-trip
        float bc[4];
#pragma unroll
        for (int nf = 0; nf < 4; ++nf)
            bc[nf] = b1[wv * 64 + nf * 16 + (lane & 15)];
#pragma unroll
        for (int mt = 0; mt < 4; ++mt) {
#pragma unroll
            for (int nf = 0; nf < 4; ++nf) {
#pragma unroll
                for (int r = 0; r < 4; ++r) {
                    int t = mt * 16 + ((lane >> 4) << 2) + r;
                    int n = wv * 64 + nf * 16 + (lane & 15);
                    Hs[t][n] = pacc[mt][nf][r] + bc[nf];
                }
            }
        }
    }
    __syncthreads();   // P (in Hs) visible block-wide

    // ---- phase 4: scan (r12 code; pvreg from LDS P rows) ----------------
#pragma unroll 1
    for (int c = 0; c < 4; ++c) {
        const int t0 = c * 16;

#pragma unroll
        for (int e = h; e < 1024; e += 512) {
            int tt = e >> 6, s = e & 63;
            int t  = t0 + tt;
            float cv = 0.f;
            if (s < t) cv = eta * lam_pow[t - 1 - s] * Gl[t][s];
            C[tt][s] = cv;
        }

        // P rows t0..t0+15 still untouched (steps overwrite only after the
        // barrier below); read them into registers now.
        float pvreg[16];
#pragma unroll
        for (int tt = 0; tt < 16; ++tt)
            pvreg[tt] = Hs[t0 + tt][h];

        __syncthreads();   // C visible; orders prev chunk's last red write

        float macc[16] = {};
        for (int s4 = 0; s4 < t0; s4 += 4) {
            float hsv0 = Hs[s4 + 0][h];
            float hsv1 = Hs[s4 + 1][h];
            float hsv2 = Hs[s4 + 2][h];
            float hsv3 = Hs[s4 + 3][h];
#pragma unroll
            for (int tt = 0; tt < 16; ++tt) {
                float4 cf = *(const float4*)&C[tt][s4];
                macc[tt] = fmaf(cf.x, hsv0, macc[tt]);
                macc[tt] = fmaf(cf.y, hsv1, macc[tt]);
                macc[tt] = fmaf(cf.z, hsv2, macc[tt]);
                macc[tt] = fmaf(cf.w, hsv3, macc[tt]);
            }
        }

        float hcur[16];
        float partial = pvreg[0] + macc[0];
#pragma unroll
        for (int tt = 0; tt < 16; ++tt) {
            const int t = t0 + tt;

            float a2x, a2y;
            if (t == 0) {
                a2x = 0.f; a2y = 0.f;
            } else {
                const int pr = (t - 1) & 1;
                float4 r0 = *(const float4*)&red[pr][0];
                float4 r1 = *(const float4*)&red[pr][4];
                float4 r2 = *(const float4*)&red[pr][8];
                float4 r3 = *(const float4*)&red[pr][12];
                float s0 = b20 + ((r0.x + r0.z) + (r1.x + r1.z)) + ((r2.x + r2.z) + (r3.x + r3.z));
                float s1 = b21 + ((r0.y + r0.w) + (r1.y + r1.w)) + ((r2.y + r2.w) + (r3.y + r3.w));
                a2x = s0; a2y = s1;
                if (h == 0) {
                    outY[((size_t)(t - 1) * BATCH + b) * 2 + 0] = 1.0f / (1.0f + __expf(-s0));
                    outY[((size_t)(t - 1) * BATCH + b) * 2 + 1] = 1.0f / (1.0f + __expf(-s1));
                }
            }

            float a1 = partial + w21v.x * a2x + w21v.y * a2y;
            float hv = 1.0f / (1.0f + __expf(-a1));
            hcur[tt] = hv;
            Hs[t][h] = hv;          // row t: P already consumed (pvreg)
            oHb[(size_t)t * (BATCH * NH)] = hv;

            float p0 = dpp_sum64(hv * w2v.x);
            float p1 = dpp_sum64(hv * w2v.y);
            if ((h & 63) == 63) {
                red[t & 1][(h >> 6) * 2]     = p0;
                red[t & 1][(h >> 6) * 2 + 1] = p1;
            }

            if (tt < 15) {
                partial = pvreg[tt + 1] + macc[tt + 1];
#pragma unroll
                for (int j = 0; j <= tt; ++j)
                    partial = fmaf(C[tt + 1][t0 + j], hcur[j], partial);
            }

            __syncthreads();
        }
    }

    {
        float4 r0 = *(const float4*)&red[63 & 1][0];
        float4 r1 = *(const float4*)&red[63 & 1][4];
        float4 r2 = *(const float4*)&red[63 & 1][8];
        float4 r3 = *(const float4*)&red[63 & 1][12];
        float s0 = b20 + ((r0.x + r0.z) + (r1.x + r1.z)) + ((r2.x + r2.z) + (r3.x + r3.z));
        float s1 = b21 + ((r0.y + r0.w) + (r1.y + r1.w)) + ((r2.y + r2.w) + (r3.y + r3.w));
        if (h == 0) {
            outY[((size_t)63 * BATCH + b) * 2 + 0] = 1.0f / (1.0f + __expf(-s0));
            outY[((size_t)63 * BATCH + b) * 2 + 1] = 1.0f / (1.0f + __expf(-s1));
        }
    }
}

// ---------------------------------------------------------------------------
extern "C" void kernel_launch(void* const* d_in, const int* in_sizes, int n_in,
                              void* d_out, int out_size, void* d_ws, size_t ws_size,
                              hipStream_t stream) {
    const float* x   = (const float*)d_in[0];
    const float* w1  = (const float*)d_in[1];
    const float* b1  = (const float*)d_in[2];
    const float* w2  = (const float*)d_in[3];
    const float* b2  = (const float*)d_in[4];
    const float* w21 = (const float*)d_in[5];
    const float* lam = (const float*)d_in[6];
    const float* eta = (const float*)d_in[7];

    float* outH = (float*)d_out;                       // [64*256*512]
    float* outY = outH + (size_t)T_STEPS * BATCH * NH; // [64*256*2]
    unsigned short* w1f = (unsigned short*)d_ws;       // 512 KB bf16 W1 frags

    w1_prep_kernel<<<128, 256, 0, stream>>>(w1, w1f);
    fused_kernel<<<256, 512, 0, stream>>>(x, w1f, b1, w2, b2, w21, lam, eta, outH, outY);
}